// Round 1
// baseline (249.517 us; speedup 1.0000x reference)
//
#include <hip/hip_runtime.h>

// MoE GLU MLP: E=8, D=1024, H=1024, K=2, N=2048 tokens, 4096 pairs.
// Grouped-GEMM implementation:
//   bucket -> convert(x, W1^T, W2^T to bf16) -> GEMM1(+SiLU-GLU) -> GEMM2 -> combine.

typedef __bf16 bf16x8 __attribute__((ext_vector_type(8)));
typedef __bf16 bf16x4 __attribute__((ext_vector_type(4)));
typedef float  f32x4  __attribute__((ext_vector_type(4)));

#define NPAIR 4096
#define NTOK  2048
#define DDIM  1024
#define HDIM  1024
#define NEXP  8

// workspace layout (bytes)
#define ORDER_I   64                      // int index of order[] in wsi
#define XB_OFF    (24576)                 // bf16 x        [2048][1024]   4 MB
#define W1T_OFF   (XB_OFF + 4194304)      // bf16 W1^T  [8][2048][1024]  32 MB
#define W2T_OFF   (W1T_OFF + 33554432)    // bf16 W2^T  [8][1024][1024]  16 MB
#define ACT_OFF   (W2T_OFF + 16777216)    // bf16 act      [5120][1024] 10.5 MB
#define YP_OFF    (ACT_OFF + 10485760)    // f32  ypair    [4096][1024]  16 MB
// total ~78 MB

__global__ void bucket_kernel(const int* __restrict__ idx, int* __restrict__ wsi) {
    __shared__ int cnt[NEXP], base[NEXP], cur[NEXP];
    const int t = threadIdx.x;
    if (t < NEXP) { cnt[t] = 0; cur[t] = 0; }
    __syncthreads();
    for (int i = t; i < NPAIR; i += 256) atomicAdd(&cnt[idx[i] & 7], 1);
    __syncthreads();
    if (t == 0) {
        int off = 0;
        for (int e = 0; e < NEXP; e++) {
            base[e] = off;
            wsi[e] = cnt[e];
            wsi[8 + e] = off;
            off += (cnt[e] + 127) & ~127;   // capacity rounded to tile
        }
    }
    __syncthreads();
    for (int i = t; i < 5120; i += 256) wsi[ORDER_I + i] = 0;
    __syncthreads();
    for (int i = t; i < NPAIR; i += 256) {
        int e = idx[i] & 7;
        int s = atomicAdd(&cur[e], 1);
        wsi[ORDER_I + base[e] + s] = i;
    }
}

__global__ void cvtx_kernel(const float* __restrict__ x, __bf16* __restrict__ xb) {
    int i = (blockIdx.x * 256 + threadIdx.x) * 4;
    float4 v = *(const float4*)(x + i);
    bf16x4 o;
    o[0] = (__bf16)v.x; o[1] = (__bf16)v.y; o[2] = (__bf16)v.z; o[3] = (__bf16)v.w;
    *(bf16x4*)(xb + i) = o;
}

// transpose+convert per expert: dst[e][c][r] = (bf16) src[e][r][c]
__global__ void tcvt_kernel(const float* __restrict__ src, __bf16* __restrict__ dst,
                            int R, int C) {
    __shared__ float t[32][33];
    const int tx = threadIdx.x & 31, ty = threadIdx.x >> 5;   // 32 x 8
    const float* s = src + (size_t)blockIdx.z * R * C;
    __bf16* d = dst + (size_t)blockIdx.z * R * C;
    const int r0 = blockIdx.y * 32, c0 = blockIdx.x * 32;
#pragma unroll
    for (int j = 0; j < 4; j++)
        t[ty + j * 8][tx] = s[(size_t)(r0 + ty + j * 8) * C + c0 + tx];
    __syncthreads();
#pragma unroll
    for (int j = 0; j < 4; j++)
        d[(size_t)(c0 + ty + j * 8) * R + r0 + tx] = (__bf16)t[tx][ty + j * 8];
}

// GEMM1: act(gathered rows) = SiLU(g) * h, hg = x @ W1[e]; 128 rows x (64 h-cols + 64 g-cols)
__global__ __launch_bounds__(256) void gemm1_kernel(const __bf16* __restrict__ xb,
                                                    const __bf16* __restrict__ w1t,
                                                    const int* __restrict__ wsi,
                                                    __bf16* __restrict__ act) {
    const int e = blockIdx.z;
    const int cnt = wsi[e];
    const int m0 = blockIdx.y * 128;
    if (m0 >= cnt) return;
    const int base = wsi[8 + e];
    const int n0 = blockIdx.x * 64;
    const int* order = wsi + ORDER_I;
    const __bf16* w1e = w1t + (size_t)e * 2048 * 1024;

    __shared__ __bf16 As[128][40];
    __shared__ __bf16 Bs[128][40];

    const int tid = threadIdx.x;
    const int lane = tid & 63, w = tid >> 6;
    const int lm = lane & 15, q = lane >> 4;

    f32x4 acc[2][8];
#pragma unroll
    for (int mt = 0; mt < 2; mt++)
#pragma unroll
        for (int nt = 0; nt < 8; nt++) acc[mt][nt] = (f32x4){0.f, 0.f, 0.f, 0.f};

    for (int k0 = 0; k0 < DDIM; k0 += 32) {
        __syncthreads();
#pragma unroll
        for (int i = 0; i < 2; i++) {
            int c = tid + i * 256;
            int row = c >> 2, ks = (c & 3) * 8;
            int m = m0 + row;
            int oi = (m < cnt) ? (base + m) : base;
            int tok = order[oi] >> 1;
            bf16x8 va = *(const bf16x8*)(xb + (size_t)tok * DDIM + k0 + ks);
            *(bf16x8*)(&As[row][ks]) = va;
            int rb = (row < 64) ? (n0 + row) : (HDIM + n0 + (row - 64));
            bf16x8 vb = *(const bf16x8*)(w1e + (size_t)rb * DDIM + k0 + ks);
            *(bf16x8*)(&Bs[row][ks]) = vb;
        }
        __syncthreads();
        bf16x8 a0 = *(const bf16x8*)(&As[w * 32 + lm][q * 8]);
        bf16x8 a1 = *(const bf16x8*)(&As[w * 32 + 16 + lm][q * 8]);
#pragma unroll
        for (int nt = 0; nt < 8; nt++) {
            bf16x8 b = *(const bf16x8*)(&Bs[nt * 16 + lm][q * 8]);
            acc[0][nt] = __builtin_amdgcn_mfma_f32_16x16x32_bf16(a0, b, acc[0][nt], 0, 0, 0);
            acc[1][nt] = __builtin_amdgcn_mfma_f32_16x16x32_bf16(a1, b, acc[1][nt], 0, 0, 0);
        }
    }
#pragma unroll
    for (int mt = 0; mt < 2; mt++)
#pragma unroll
        for (int nt = 0; nt < 4; nt++)
#pragma unroll
            for (int r = 0; r < 4; r++) {
                int m = w * 32 + mt * 16 + q * 4 + r;
                if (m0 + m < cnt) {
                    float h = acc[mt][nt][r];
                    float g = acc[mt][nt + 4][r];
                    float a = h * (g / (1.f + __expf(-g)));
                    act[(size_t)(base + m0 + m) * HDIM + n0 + nt * 16 + lm] = (__bf16)a;
                }
            }
}

// GEMM2: ypair[pair] = act @ W2[e]; scatter rows by order[]
__global__ __launch_bounds__(256) void gemm2_kernel(const __bf16* __restrict__ act,
                                                    const __bf16* __restrict__ w2t,
                                                    const int* __restrict__ wsi,
                                                    float* __restrict__ yp) {
    const int e = blockIdx.z;
    const int cnt = wsi[e];
    const int m0 = blockIdx.y * 128;
    if (m0 >= cnt) return;
    const int base = wsi[8 + e];
    const int n0 = blockIdx.x * 128;
    const int* order = wsi + ORDER_I;
    const __bf16* w2e = w2t + (size_t)e * 1024 * 1024;

    __shared__ __bf16 As[128][40];
    __shared__ __bf16 Bs[128][40];

    const int tid = threadIdx.x;
    const int lane = tid & 63, w = tid >> 6;
    const int lm = lane & 15, q = lane >> 4;

    f32x4 acc[2][8];
#pragma unroll
    for (int mt = 0; mt < 2; mt++)
#pragma unroll
        for (int nt = 0; nt < 8; nt++) acc[mt][nt] = (f32x4){0.f, 0.f, 0.f, 0.f};

    for (int k0 = 0; k0 < HDIM; k0 += 32) {
        __syncthreads();
#pragma unroll
        for (int i = 0; i < 2; i++) {
            int c = tid + i * 256;
            int row = c >> 2, ks = (c & 3) * 8;
            int m = m0 + row;
            int ar = (m < cnt) ? (base + m) : base;
            bf16x8 va = *(const bf16x8*)(act + (size_t)ar * HDIM + k0 + ks);
            *(bf16x8*)(&As[row][ks]) = va;
            bf16x8 vb = *(const bf16x8*)(w2e + (size_t)(n0 + row) * HDIM + k0 + ks);
            *(bf16x8*)(&Bs[row][ks]) = vb;
        }
        __syncthreads();
        bf16x8 a0 = *(const bf16x8*)(&As[w * 32 + lm][q * 8]);
        bf16x8 a1 = *(const bf16x8*)(&As[w * 32 + 16 + lm][q * 8]);
#pragma unroll
        for (int nt = 0; nt < 8; nt++) {
            bf16x8 b = *(const bf16x8*)(&Bs[nt * 16 + lm][q * 8]);
            acc[0][nt] = __builtin_amdgcn_mfma_f32_16x16x32_bf16(a0, b, acc[0][nt], 0, 0, 0);
            acc[1][nt] = __builtin_amdgcn_mfma_f32_16x16x32_bf16(a1, b, acc[1][nt], 0, 0, 0);
        }
    }
#pragma unroll
    for (int mt = 0; mt < 2; mt++)
#pragma unroll
        for (int nt = 0; nt < 8; nt++)
#pragma unroll
            for (int r = 0; r < 4; r++) {
                int m = w * 32 + mt * 16 + q * 4 + r;
                int gm = m0 + m;
                if (gm < cnt) {
                    int pi = order[base + gm];
                    yp[(size_t)pi * DDIM + n0 + nt * 16 + lm] = acc[mt][nt][r];
                }
            }
}

__global__ void combine_kernel(const float* __restrict__ yp, const float* __restrict__ p,
                               float* __restrict__ out) {
    int id = blockIdx.x * 256 + threadIdx.x;
    int n = id >> 8;
    int c = (id & 255) << 2;
    const float4 v0 = *(const float4*)(yp + (size_t)(2 * n) * DDIM + c);
    const float4 v1 = *(const float4*)(yp + (size_t)(2 * n + 1) * DDIM + c);
    float p0 = p[2 * n], p1 = p[2 * n + 1];
    float4 o;
    o.x = p0 * v0.x + p1 * v1.x;
    o.y = p0 * v0.y + p1 * v1.y;
    o.z = p0 * v0.z + p1 * v1.z;
    o.w = p0 * v0.w + p1 * v1.w;
    *(float4*)(out + (size_t)n * DDIM + c) = o;
}

extern "C" void kernel_launch(void* const* d_in, const int* in_sizes, int n_in,
                              void* d_out, int out_size, void* d_ws, size_t ws_size,
                              hipStream_t stream) {
    (void)in_sizes; (void)n_in; (void)out_size; (void)ws_size;
    const float* x   = (const float*)d_in[0];
    const float* p   = (const float*)d_in[1];
    const int* eidx  = (const int*)d_in[2];
    const float* W1  = (const float*)d_in[3];
    const float* W2  = (const float*)d_in[4];
    float* out = (float*)d_out;

    char* ws = (char*)d_ws;
    int* wsi     = (int*)ws;
    __bf16* xb   = (__bf16*)(ws + XB_OFF);
    __bf16* w1t  = (__bf16*)(ws + W1T_OFF);
    __bf16* w2t  = (__bf16*)(ws + W2T_OFF);
    __bf16* act  = (__bf16*)(ws + ACT_OFF);
    float* yp    = (float*)(ws + YP_OFF);

    bucket_kernel<<<1, 256, 0, stream>>>(eidx, wsi);
    cvtx_kernel<<<(NTOK * DDIM) / (256 * 4), 256, 0, stream>>>(x, xb);
    tcvt_kernel<<<dim3(64, 32, NEXP), 256, 0, stream>>>(W1, w1t, DDIM, 2 * HDIM);
    tcvt_kernel<<<dim3(32, 32, NEXP), 256, 0, stream>>>(W2, w2t, HDIM, DDIM);
    gemm1_kernel<<<dim3(16, 32, NEXP), 256, 0, stream>>>(xb, w1t, wsi, act);
    gemm2_kernel<<<dim3(8, 32, NEXP), 256, 0, stream>>>(act, w2t, wsi, yp);
    combine_kernel<<<NTOK, 256, 0, stream>>>(yp, p, out);
}

// Round 2
// 227.043 us; speedup vs baseline: 1.0990x; 1.0990x over previous
//
#include <hip/hip_runtime.h>

// MoE GLU MLP: E=8, D=1024, H=1024, K=2, N=2048 tokens, 4096 pairs.
// Grouped-GEMM, m97-style: global_load_lds staging, unpadded [128][32] LDS,
// 4x4 MFMA frags/wave, hoisted gather addressing.

typedef __bf16 bf16x8 __attribute__((ext_vector_type(8)));
typedef __bf16 bf16x4 __attribute__((ext_vector_type(4)));
typedef float  f32x4  __attribute__((ext_vector_type(4)));

#define NPAIR 4096
#define NTOK  2048
#define DDIM  1024
#define HDIM  1024
#define NEXP  8

// workspace layout (bytes)
#define ORDER_I   64                      // int index of order[] in wsi
#define XB_OFF    (24576)                 // bf16 x        [2048][1024]   4 MB
#define W1T_OFF   (XB_OFF + 4194304)      // bf16 W1^T  [8][2048][1024]  32 MB
#define W2T_OFF   (W1T_OFF + 33554432)    // bf16 W2^T  [8][1024][1024]  16 MB
#define ACT_OFF   (W2T_OFF + 16777216)    // bf16 act      [5120][1024] 10.5 MB
#define YP_OFF    (ACT_OFF + 10485760)    // f32  ypair    [4096][1024]  16 MB

#define GLOAD_LDS16(g, l) \
    __builtin_amdgcn_global_load_lds( \
        (const __attribute__((address_space(1))) void*)(g), \
        (__attribute__((address_space(3))) void*)(l), 16, 0, 0)

__global__ void bucket_kernel(const int* __restrict__ idx, int* __restrict__ wsi) {
    __shared__ int cnt[NEXP], base[NEXP], cur[NEXP];
    const int t = threadIdx.x;
    if (t < NEXP) { cnt[t] = 0; cur[t] = 0; }
    __syncthreads();
    for (int i = t; i < NPAIR; i += 256) atomicAdd(&cnt[idx[i] & 7], 1);
    __syncthreads();
    if (t == 0) {
        int off = 0;
        for (int e = 0; e < NEXP; e++) {
            base[e] = off;
            wsi[e] = cnt[e];
            wsi[8 + e] = off;
            off += (cnt[e] + 127) & ~127;   // capacity rounded to tile
        }
    }
    __syncthreads();
    for (int i = t; i < 5120; i += 256) wsi[ORDER_I + i] = 0;
    __syncthreads();
    for (int i = t; i < NPAIR; i += 256) {
        int e = idx[i] & 7;
        int s = atomicAdd(&cur[e], 1);
        wsi[ORDER_I + base[e] + s] = i;
    }
}

__global__ void cvtx_kernel(const float* __restrict__ x, __bf16* __restrict__ xb) {
    int i = (blockIdx.x * 256 + threadIdx.x) * 4;
    float4 v = *(const float4*)(x + i);
    bf16x4 o;
    o[0] = (__bf16)v.x; o[1] = (__bf16)v.y; o[2] = (__bf16)v.z; o[3] = (__bf16)v.w;
    *(bf16x4*)(xb + i) = o;
}

// transpose+convert per expert: dst[e][c][r] = (bf16) src[e][r][c], 64x64 tiles
__global__ __launch_bounds__(256) void tcvt_kernel(const float* __restrict__ src,
                                                   __bf16* __restrict__ dst,
                                                   int R, int C) {
    __shared__ float t[64][65];
    const int tid = threadIdx.x;
    const float* s = src + (size_t)blockIdx.z * R * C;
    __bf16* d = dst + (size_t)blockIdx.z * R * C;
    const int r0 = blockIdx.y * 64, c0 = blockIdx.x * 64;
    const int lr = tid >> 4;            // 0..15
    const int lc = (tid & 15) * 4;      // 0..60
#pragma unroll
    for (int p = 0; p < 4; p++) {
        int r = p * 16 + lr;
        float4 v = *(const float4*)(s + (size_t)(r0 + r) * C + c0 + lc);
        t[r][lc] = v.x; t[r][lc + 1] = v.y; t[r][lc + 2] = v.z; t[r][lc + 3] = v.w;
    }
    __syncthreads();
#pragma unroll
    for (int p = 0; p < 4; p++) {
        int c = p * 16 + lr;
        bf16x4 o;
#pragma unroll
        for (int i = 0; i < 4; i++) o[i] = (__bf16)t[lc + i][c];
        *(bf16x4*)(d + (size_t)(c0 + c) * R + r0 + lc) = o;
    }
}

// GEMM1: 128 rows x 64 output cols per block; B tile = 128 LDS rows interleaving
// h (W1T rows n0+..) and g (W1T rows 1024+n0+..) halves so SiLU fuses per-thread.
__global__ __launch_bounds__(256) void gemm1_kernel(const __bf16* __restrict__ xb,
                                                    const __bf16* __restrict__ w1t,
                                                    const int* __restrict__ wsi,
                                                    __bf16* __restrict__ act) {
    const int e = blockIdx.z;
    const int cnt = wsi[e];
    const int m0 = blockIdx.y * 128;
    if (m0 >= cnt) return;
    const int base = wsi[8 + e];
    const int n0 = blockIdx.x * 64;
    const int* order = wsi + ORDER_I;
    const __bf16* w1e = w1t + (size_t)e * 2048 * 1024;

    __shared__ __align__(16) __bf16 As[128][32];
    __shared__ __align__(16) __bf16 Bs[128][32];

    const int tid = threadIdx.x;
    const int lane = tid & 63, w = tid >> 6;
    const int lm = lane & 15, q = lane >> 4;
    const int wm = w & 1, wn = w >> 1;

    // hoisted staging addresses: chunk c = j*256 + tid; LDS byte offset = c*16
    const __bf16* ga[2];
    const __bf16* gb[2];
#pragma unroll
    for (int j = 0; j < 2; j++) {
        int c = j * 256 + tid;
        int r = c >> 2, ks = (c & 3) * 8;
        int m = m0 + r; if (m >= cnt) m = cnt - 1;
        int tok = order[base + m] >> 1;
        ga[j] = xb + (size_t)tok * DDIM + ks;
        int half = r >> 6, rr = r & 63;
        int rb = (rr < 32) ? (n0 + half * 32 + rr)
                           : (HDIM + n0 + half * 32 + (rr - 32));
        gb[j] = w1e + (size_t)rb * DDIM + ks;
    }

    f32x4 acc[4][4];
#pragma unroll
    for (int mt = 0; mt < 4; mt++)
#pragma unroll
        for (int nt = 0; nt < 4; nt++) acc[mt][nt] = (f32x4){0.f, 0.f, 0.f, 0.f};

    for (int k0 = 0; k0 < DDIM; k0 += 32) {
        __syncthreads();
#pragma unroll
        for (int j = 0; j < 2; j++) {
            int c = j * 256 + tid;
            GLOAD_LDS16(ga[j], (char*)&As[0][0] + c * 16);
            GLOAD_LDS16(gb[j], (char*)&Bs[0][0] + c * 16);
            ga[j] += 32; gb[j] += 32;
        }
        __syncthreads();
        bf16x8 af[4];
#pragma unroll
        for (int mt = 0; mt < 4; mt++)
            af[mt] = *(const bf16x8*)(&As[wm * 64 + mt * 16 + lm][q * 8]);
#pragma unroll
        for (int nt = 0; nt < 4; nt++) {
            bf16x8 b = *(const bf16x8*)(&Bs[wn * 64 + nt * 16 + lm][q * 8]);
#pragma unroll
            for (int mt = 0; mt < 4; mt++)
                acc[mt][nt] = __builtin_amdgcn_mfma_f32_16x16x32_bf16(af[mt], b, acc[mt][nt], 0, 0, 0);
        }
    }

#pragma unroll
    for (int mt = 0; mt < 4; mt++) {
        int mbase = m0 + wm * 64 + mt * 16 + q * 4;
#pragma unroll
        for (int ntp = 0; ntp < 2; ntp++) {
            int col = n0 + wn * 32 + ntp * 16 + lm;
#pragma unroll
            for (int r = 0; r < 4; r++) {
                int m = mbase + r;
                if (m < cnt) {
                    float h = acc[mt][ntp][r];
                    float g = acc[mt][ntp + 2][r];
                    float a = h * (g / (1.f + __expf(-g)));
                    act[(size_t)(base + m) * HDIM + col] = (__bf16)a;
                }
            }
        }
    }
}

// GEMM2: 128 rows x 128 cols per block; scatter rows to ypair by order[]
__global__ __launch_bounds__(256) void gemm2_kernel(const __bf16* __restrict__ act,
                                                    const __bf16* __restrict__ w2t,
                                                    const int* __restrict__ wsi,
                                                    float* __restrict__ yp) {
    const int e = blockIdx.z;
    const int cnt = wsi[e];
    const int m0 = blockIdx.y * 128;
    if (m0 >= cnt) return;
    const int base = wsi[8 + e];
    const int n0 = blockIdx.x * 128;
    const int* order = wsi + ORDER_I;
    const __bf16* w2e = w2t + (size_t)e * 1024 * 1024;

    __shared__ __align__(16) __bf16 As[128][32];
    __shared__ __align__(16) __bf16 Bs[128][32];

    const int tid = threadIdx.x;
    const int lane = tid & 63, w = tid >> 6;
    const int lm = lane & 15, q = lane >> 4;
    const int wm = w & 1, wn = w >> 1;

    const __bf16* ga[2];
    const __bf16* gb[2];
#pragma unroll
    for (int j = 0; j < 2; j++) {
        int c = j * 256 + tid;
        int r = c >> 2, ks = (c & 3) * 8;
        ga[j] = act + (size_t)(base + m0 + r) * HDIM + ks;   // pad rows hold tiny poison, masked at write
        gb[j] = w2e + (size_t)(n0 + r) * HDIM + ks;
    }

    f32x4 acc[4][4];
#pragma unroll
    for (int mt = 0; mt < 4; mt++)
#pragma unroll
        for (int nt = 0; nt < 4; nt++) acc[mt][nt] = (f32x4){0.f, 0.f, 0.f, 0.f};

    for (int k0 = 0; k0 < HDIM; k0 += 32) {
        __syncthreads();
#pragma unroll
        for (int j = 0; j < 2; j++) {
            int c = j * 256 + tid;
            GLOAD_LDS16(ga[j], (char*)&As[0][0] + c * 16);
            GLOAD_LDS16(gb[j], (char*)&Bs[0][0] + c * 16);
            ga[j] += 32; gb[j] += 32;
        }
        __syncthreads();
        bf16x8 af[4];
#pragma unroll
        for (int mt = 0; mt < 4; mt++)
            af[mt] = *(const bf16x8*)(&As[wm * 64 + mt * 16 + lm][q * 8]);
#pragma unroll
        for (int nt = 0; nt < 4; nt++) {
            bf16x8 b = *(const bf16x8*)(&Bs[wn * 64 + nt * 16 + lm][q * 8]);
#pragma unroll
            for (int mt = 0; mt < 4; mt++)
                acc[mt][nt] = __builtin_amdgcn_mfma_f32_16x16x32_bf16(af[mt], b, acc[mt][nt], 0, 0, 0);
        }
    }

    // hoist scatter indices
    int pi[4][4];
#pragma unroll
    for (int mt = 0; mt < 4; mt++)
#pragma unroll
        for (int r = 0; r < 4; r++) {
            int gm = m0 + wm * 64 + mt * 16 + q * 4 + r;
            pi[mt][r] = (gm < cnt) ? order[base + gm] : -1;
        }
#pragma unroll
    for (int mt = 0; mt < 4; mt++)
#pragma unroll
        for (int nt = 0; nt < 4; nt++) {
            int col = n0 + wn * 64 + nt * 16 + lm;
#pragma unroll
            for (int r = 0; r < 4; r++) {
                if (pi[mt][r] >= 0)
                    yp[(size_t)pi[mt][r] * DDIM + col] = acc[mt][nt][r];
            }
        }
}

__global__ void combine_kernel(const float* __restrict__ yp, const float* __restrict__ p,
                               float* __restrict__ out) {
    int id = blockIdx.x * 256 + threadIdx.x;
    int n = id >> 8;
    int c = (id & 255) << 2;
    const float4 v0 = *(const float4*)(yp + (size_t)(2 * n) * DDIM + c);
    const float4 v1 = *(const float4*)(yp + (size_t)(2 * n + 1) * DDIM + c);
    float p0 = p[2 * n], p1 = p[2 * n + 1];
    float4 o;
    o.x = p0 * v0.x + p1 * v1.x;
    o.y = p0 * v0.y + p1 * v1.y;
    o.z = p0 * v0.z + p1 * v1.z;
    o.w = p0 * v0.w + p1 * v1.w;
    *(float4*)(out + (size_t)n * DDIM + c) = o;
}

extern "C" void kernel_launch(void* const* d_in, const int* in_sizes, int n_in,
                              void* d_out, int out_size, void* d_ws, size_t ws_size,
                              hipStream_t stream) {
    (void)in_sizes; (void)n_in; (void)out_size; (void)ws_size;
    const float* x   = (const float*)d_in[0];
    const float* p   = (const float*)d_in[1];
    const int* eidx  = (const int*)d_in[2];
    const float* W1  = (const float*)d_in[3];
    const float* W2  = (const float*)d_in[4];
    float* out = (float*)d_out;

    char* ws = (char*)d_ws;
    int* wsi     = (int*)ws;
    __bf16* xb   = (__bf16*)(ws + XB_OFF);
    __bf16* w1t  = (__bf16*)(ws + W1T_OFF);
    __bf16* w2t  = (__bf16*)(ws + W2T_OFF);
    __bf16* act  = (__bf16*)(ws + ACT_OFF);
    float* yp    = (float*)(ws + YP_OFF);

    bucket_kernel<<<1, 256, 0, stream>>>(eidx, wsi);
    cvtx_kernel<<<(NTOK * DDIM) / (256 * 4), 256, 0, stream>>>(x, xb);
    tcvt_kernel<<<dim3(32, 16, NEXP), 256, 0, stream>>>(W1, w1t, DDIM, 2 * HDIM);
    tcvt_kernel<<<dim3(16, 16, NEXP), 256, 0, stream>>>(W2, w2t, HDIM, DDIM);
    gemm1_kernel<<<dim3(16, 32, NEXP), 256, 0, stream>>>(xb, w1t, wsi, act);
    gemm2_kernel<<<dim3(8, 32, NEXP), 256, 0, stream>>>(act, w2t, wsi, yp);
    combine_kernel<<<NTOK, 256, 0, stream>>>(yp, p, out);
}